// Round 2
// baseline (302.881 us; speedup 1.0000x reference)
//
#include <hip/hip_runtime.h>
#include <hip/hip_cooperative_groups.h>

namespace cg = cooperative_groups;

// B=4, T=4096, E=1024, H=64.
// out = Q @ M_b,  M_b = (1/32) * K_b^T V_b,  Q/K/V = idx@W + b   (linear attention:
// reference applies no mask/softmax). Scale folded into Wk/bk.
//
// R9: single cooperative kernel, 512 blocks (exactly 2/CU, LDS 70.4KB -> fits 2).
// Phases: [1] W->WB fragment prep; [2] per-block 32-row QKV (Q,Kt,Vt stay in LDS,
// never global); [3a] per-block M-tile = Kt_loc @ Vt_loc^T -> part[block] (16KB);
// [3b] 128-way tree reduce -> Mt bf16 transposed; [4] out = Q_lds @ Mt.
// Global traffic: idx 64MB R + part 8MB W/R + out 4MB W (~85MB total vs R8's ~105MB
// + 4 launches). 3 grid.sync()s replace 3 launch gaps. R8 4-kernel path kept as
// fallback if cooperative launch is rejected.

typedef __attribute__((ext_vector_type(8))) short bf16x8;   // 8 bf16 = 4 VGPRs
typedef __attribute__((ext_vector_type(4))) float f32x4;    // MFMA C/D

#define MFMA16(a, b, c) __builtin_amdgcn_mfma_f32_16x16x32_bf16((a), (b), (c), 0, 0, 0)

__device__ __forceinline__ unsigned short f2bf(float f) {
    unsigned int u = __float_as_uint(f);
    u += 0x7fffu + ((u >> 16) & 1u);          // round-to-nearest-even
    return (unsigned short)(u >> 16);
}

// ---------------------------------------------------------------------------
// The mega-kernel.
__global__ __launch_bounds__(256, 2) void mega(
    const float* __restrict__ idx,
    const float* __restrict__ Wq, const float* __restrict__ bq_,
    const float* __restrict__ Wk, const float* __restrict__ bk_,
    const float* __restrict__ Wv, const float* __restrict__ bv_,
    unsigned short* __restrict__ WB, float* __restrict__ part,
    unsigned short* __restrict__ Mt, float* __restrict__ out) {
    __shared__ unsigned short As[32 * 1032];   // 66048 B (stage; reused ph3 as Lk/Lv)
    __shared__ unsigned short Lq[32 * 68];     // 4352 B, persists phase2 -> phase4
    unsigned short* Lk = As;                   // [64][36] bf16, Kt local (h-major)
    unsigned short* Lv = As + 64 * 36;         // [64][36] bf16, Vt local

    const int tid = threadIdx.x, lane = tid & 63, w = tid >> 6;
    const int bid = blockIdx.x;
    cg::grid_group grid = cg::this_grid();

    // ---- phase 1: weights -> MFMA-fragment order (96 blocks' worth) ----
    // Chunk t holds W^T[n][k]: n = nt*16+(lane&15), k = kk*32+(lane>>4)*8+j.
    if (bid < 96) {
        int t = bid * 256 + tid;               // [0, 24576)
        int kki = t / 768;
        int rem = t - kki * 768;
        int nt = rem >> 6, l = rem & 63;
        int n = nt * 16 + (l & 15);
        int kb = kki * 32 + ((l >> 4) * 8);
        int mm = n >> 6, h = n & 63;
        const float* W = (mm == 0) ? Wq : (mm == 1) ? Wk : Wv;
        float sc = (mm == 1) ? 0.03125f : 1.0f;
        bf16x8 v;
        #pragma unroll
        for (int j = 0; j < 8; j++) v[j] = (short)f2bf(W[(size_t)(kb + j) * 64 + h] * sc);
        *(bf16x8*)(WB + (size_t)t * 8) = v;
    }
    grid.sync();

    // ---- phase 2: QKV for this block's 32 rows ----
    const int r0 = bid * 32;
    {
        const float* src = idx + (size_t)(r0 + w * 8) * 1024;
        #pragma unroll
        for (int batch = 0; batch < 4; batch++) {
            float4 v[8];
            #pragma unroll
            for (int j = 0; j < 8; j++)
                v[j] = *(const float4*)(src + (size_t)(batch * 8 + j) * 256 + lane * 4);
            #pragma unroll
            for (int j = 0; j < 8; j++) {
                int i   = batch * 8 + j;
                int row = w * 8 + (i >> 2);
                int k   = (i & 3) * 256 + lane * 4;
                unsigned int lo = ((unsigned int)f2bf(v[j].y) << 16) | f2bf(v[j].x);
                unsigned int hi = ((unsigned int)f2bf(v[j].w) << 16) | f2bf(v[j].z);
                uint2 p; p.x = lo; p.y = hi;
                *(uint2*)(As + (size_t)row * 1032 + k) = p;
            }
        }
    }
    __syncthreads();

    const f32x4 z4 = {0.f, 0.f, 0.f, 0.f};
    f32x4 acc[2][3] = {{z4, z4, z4}, {z4, z4, z4}};
    {
        const unsigned short* a_base0 = As + (size_t)(lane & 15) * 1032 + ((lane >> 4) * 8);
        const unsigned short* a_base1 = a_base0 + 16 * 1032;
        bf16x8 a_c[2], b0[3], b1[3], b2[3];
        a_c[0] = *(const bf16x8*)a_base0;
        a_c[1] = *(const bf16x8*)a_base1;
        {
            const unsigned short* Bp0 = WB + (size_t)(lane * 8);
            const unsigned short* Bp1 = WB + (size_t)(12 * 64 + lane) * 8;
            #pragma unroll
            for (int j = 0; j < 3; j++) {
                b0[j] = *(const bf16x8*)(Bp0 + (w + j * 4) * 512);
                b1[j] = *(const bf16x8*)(Bp1 + (w + j * 4) * 512);
                b2[j] = b1[j];
            }
        }
        for (int kk = 0; kk < 32; kk++) {
            bf16x8 na0 = a_c[0], na1 = a_c[1];
            if (kk < 30) {
                const unsigned short* Bp = WB + (size_t)(((kk + 2) * 12) * 64 + lane) * 8;
                #pragma unroll
                for (int j = 0; j < 3; j++) b2[j] = *(const bf16x8*)(Bp + (w + j * 4) * 512);
            }
            if (kk < 31) {
                na0 = *(const bf16x8*)(a_base0 + (kk + 1) * 32);
                na1 = *(const bf16x8*)(a_base1 + (kk + 1) * 32);
            }
            #pragma unroll
            for (int j = 0; j < 3; j++) {
                acc[0][j] = MFMA16(a_c[0], b0[j], acc[0][j]);
                acc[1][j] = MFMA16(a_c[1], b0[j], acc[1][j]);
            }
            #pragma unroll
            for (int j = 0; j < 3; j++) { b0[j] = b1[j]; b1[j] = b2[j]; }
            a_c[0] = na0; a_c[1] = na1;
        }
    }

    // ---- epilogue: Q/Kt/Vt into LDS only (As A-reads done -> reuse as Lk/Lv) ----
    __syncthreads();
    {
        const int h     = w * 16 + (lane & 15);
        const int rbase = (lane >> 4) * 4;
        float bias0 = bq_[h], bias1 = bk_[h] * 0.03125f, bias2 = bv_[h];
        #pragma unroll
        for (int rf = 0; rf < 2; rf++) {
            #pragma unroll
            for (int reg = 0; reg < 4; reg++) {
                int r = rf * 16 + rbase + reg;
                Lq[r * 68 + h] = f2bf(acc[rf][0][reg] + bias0);
                Lk[h * 36 + r] = f2bf(acc[rf][1][reg] + bias1);   // [h][t] pad 36
                Lv[h * 36 + r] = f2bf(acc[rf][2][reg] + bias2);
            }
        }
    }
    __syncthreads();

    // ---- phase 3a: this block's M contribution (K=t=32, one MFMA per frag) ----
    {
        const int tq = (lane >> 4) * 8;
        bf16x8 a = *(const bf16x8*)&Lk[(16 * w + (lane & 15)) * 36 + tq];
        f32x4 accM[4];
        #pragma unroll
        for (int nt = 0; nt < 4; nt++) {
            bf16x8 bb = *(const bf16x8*)&Lv[(nt * 16 + (lane & 15)) * 36 + tq];
            accM[nt] = MFMA16(a, bb, z4);
        }
        float* P = part + (size_t)bid * 4096;
        const int rowb = 16 * w + (lane >> 4) * 4;
        #pragma unroll
        for (int nt = 0; nt < 4; nt++)
            #pragma unroll
            for (int reg = 0; reg < 4; reg++)
                P[(rowb + reg) * 64 + nt * 16 + (lane & 15)] = accM[nt][reg];
    }
    grid.sync();

    // ---- phase 3b: reduce 128 partial tiles per batch -> Mt[b][h2][h1] bf16 ----
    if (bid < 64) {
        int i = bid * 256 + tid;               // 16384 = 4 * 64 * 64
        int b = i >> 12, e = i & 4095;         // e = h1*64 + h2
        const float* Pp = part + (size_t)(b * 128) * 4096 + e;
        float s0 = 0.f, s1 = 0.f, s2 = 0.f, s3 = 0.f;
        #pragma unroll 4
        for (int j = 0; j < 128; j += 4) {
            s0 += Pp[(size_t)(j + 0) * 4096];
            s1 += Pp[(size_t)(j + 1) * 4096];
            s2 += Pp[(size_t)(j + 2) * 4096];
            s3 += Pp[(size_t)(j + 3) * 4096];
        }
        Mt[(size_t)b * 4096 + (e & 63) * 64 + (e >> 6)] = f2bf((s0 + s1) + (s2 + s3));
    }
    grid.sync();

    // ---- phase 4: out[r0..r0+32] = Q_lds @ M (B-frags direct from L2-hot Mt) ----
    {
        const int rf = w >> 1, np = w & 1;     // row-frag, nt-pair
        const int b  = r0 >> 12;
        const int kq = (lane >> 4) * 8;
        f32x4 acc4[2] = {z4, z4};
        #pragma unroll
        for (int ks = 0; ks < 2; ks++) {
            bf16x8 a = *(const bf16x8*)&Lq[(rf * 16 + (lane & 15)) * 68 + ks * 32 + kq];
            #pragma unroll
            for (int j = 0; j < 2; j++) {
                int nt = np * 2 + j;
                bf16x8 bb = *(const bf16x8*)&Mt[(size_t)b * 4096 +
                                                (nt * 16 + (lane & 15)) * 64 + ks * 32 + kq];
                acc4[j] = MFMA16(a, bb, acc4[j]);
            }
        }
        const int rowb = r0 + rf * 16 + (lane >> 4) * 4;
        #pragma unroll
        for (int j = 0; j < 2; j++)
            #pragma unroll
            for (int reg = 0; reg < 4; reg++)
                out[(size_t)(rowb + reg) * 64 + (np * 2 + j) * 16 + (lane & 15)] = acc4[j][reg];
    }
}

// ===========================================================================
// Fallback path (R8, 4 kernels) — used only if cooperative launch is rejected.
// ===========================================================================
__global__ void prep(const float* __restrict__ Wq, const float* __restrict__ Wk,
                     const float* __restrict__ Wv, unsigned short* __restrict__ WB,
                     float* __restrict__ Mf) {
    int t = blockIdx.x * 256 + threadIdx.x;
    if (t < 16384) Mf[t] = 0.f;
    int kki = t / 768;
    int rem = t - kki * 768;
    int nt = rem >> 6, lane = rem & 63;
    int n = nt * 16 + (lane & 15);
    int kb = kki * 32 + ((lane >> 4) * 8);
    int mm = n >> 6, h = n & 63;
    const float* W = (mm == 0) ? Wq : (mm == 1) ? Wk : Wv;
    float sc = (mm == 1) ? 0.03125f : 1.0f;
    bf16x8 v;
    #pragma unroll
    for (int j = 0; j < 8; j++) v[j] = (short)f2bf(W[(size_t)(kb + j) * 64 + h] * sc);
    *(bf16x8*)(WB + (size_t)t * 8) = v;
}

__global__ __launch_bounds__(256, 2) void qkv(
    const float* __restrict__ idx, const unsigned short* __restrict__ WB,
    const float* __restrict__ bq, const float* __restrict__ bk, const float* __restrict__ bv,
    unsigned short* __restrict__ Q, unsigned short* __restrict__ Kt,
    unsigned short* __restrict__ Vt) {
    __shared__ unsigned short As[32 * 1032];
    const int lane = threadIdx.x & 63, w = threadIdx.x >> 6;
    const int r0 = blockIdx.x * 32;
    const float* src = idx + (size_t)(r0 + w * 8) * 1024;
    #pragma unroll
    for (int batch = 0; batch < 4; batch++) {
        float4 v[8];
        #pragma unroll
        for (int j = 0; j < 8; j++)
            v[j] = *(const float4*)(src + (size_t)(batch * 8 + j) * 256 + lane * 4);
        #pragma unroll
        for (int j = 0; j < 8; j++) {
            int i   = batch * 8 + j;
            int row = w * 8 + (i >> 2);
            int k   = (i & 3) * 256 + lane * 4;
            unsigned int lo = ((unsigned int)f2bf(v[j].y) << 16) | f2bf(v[j].x);
            unsigned int hi = ((unsigned int)f2bf(v[j].w) << 16) | f2bf(v[j].z);
            uint2 p; p.x = lo; p.y = hi;
            *(uint2*)(As + (size_t)row * 1032 + k) = p;
        }
    }
    __syncthreads();
    const f32x4 z4 = {0.f, 0.f, 0.f, 0.f};
    f32x4 acc[2][3] = {{z4, z4, z4}, {z4, z4, z4}};
    const unsigned short* a_base0 = As + (size_t)(lane & 15) * 1032 + ((lane >> 4) * 8);
    const unsigned short* a_base1 = a_base0 + 16 * 1032;
    bf16x8 a_c[2], b0[3], b1[3], b2[3];
    a_c[0] = *(const bf16x8*)a_base0;
    a_c[1] = *(const bf16x8*)a_base1;
    {
        const unsigned short* Bp0 = WB + (size_t)(lane * 8);
        const unsigned short* Bp1 = WB + (size_t)(12 * 64 + lane) * 8;
        #pragma unroll
        for (int j = 0; j < 3; j++) {
            b0[j] = *(const bf16x8*)(Bp0 + (w + j * 4) * 512);
            b1[j] = *(const bf16x8*)(Bp1 + (w + j * 4) * 512);
            b2[j] = b1[j];
        }
    }
    for (int kk = 0; kk < 32; kk++) {
        bf16x8 na0 = a_c[0], na1 = a_c[1];
        if (kk < 30) {
            const unsigned short* Bp = WB + (size_t)(((kk + 2) * 12) * 64 + lane) * 8;
            #pragma unroll
            for (int j = 0; j < 3; j++) b2[j] = *(const bf16x8*)(Bp + (w + j * 4) * 512);
        }
        if (kk < 31) {
            na0 = *(const bf16x8*)(a_base0 + (kk + 1) * 32);
            na1 = *(const bf16x8*)(a_base1 + (kk + 1) * 32);
        }
        #pragma unroll
        for (int j = 0; j < 3; j++) {
            acc[0][j] = MFMA16(a_c[0], b0[j], acc[0][j]);
            acc[1][j] = MFMA16(a_c[1], b0[j], acc[1][j]);
        }
        #pragma unroll
        for (int j = 0; j < 3; j++) { b0[j] = b1[j]; b1[j] = b2[j]; }
        a_c[0] = na0; a_c[1] = na1;
    }
    __syncthreads();
    unsigned short* Lq = As;
    unsigned short* Lk = As + 2048;
    unsigned short* Lv = As + 4096;
    const int h     = w * 16 + (lane & 15);
    const int rbase = (lane >> 4) * 4;
    {
        float bias0 = bq[h], bias1 = bk[h] * 0.03125f, bias2 = bv[h];
        #pragma unroll
        for (int rf = 0; rf < 2; rf++) {
            #pragma unroll
            for (int reg = 0; reg < 4; reg++) {
                int r = rf * 16 + rbase + reg;
                Lq[r * 64 + h] = f2bf(acc[rf][0][reg] + bias0);
                Lk[h * 32 + r] = f2bf(acc[rf][1][reg] + bias1);
                Lv[h * 32 + r] = f2bf(acc[rf][2][reg] + bias2);
            }
        }
    }
    __syncthreads();
    {
        const int tt = threadIdx.x;
        int qr = tt >> 3, qh = (tt & 7) * 8;
        *(uint4*)(Q + (size_t)(r0 + qr) * 64 + qh) = *(const uint4*)(Lq + qr * 64 + qh);
        int b = r0 >> 12, t0 = r0 & 4095;
        int hh = tt >> 2, tc = (tt & 3) * 8;
        *(uint4*)(Kt + (size_t)b * 262144 + hh * 4096 + t0 + tc) =
            *(const uint4*)(Lk + hh * 32 + tc);
        *(uint4*)(Vt + (size_t)b * 262144 + hh * 4096 + t0 + tc) =
            *(const uint4*)(Lv + hh * 32 + tc);
    }
}

__global__ __launch_bounds__(256) void ktv(
    const unsigned short* __restrict__ Kt, const unsigned short* __restrict__ Vt,
    float* __restrict__ Mf) {
    const int lane = threadIdx.x & 63, wave = threadIdx.x >> 6;
    const int c = blockIdx.x, b = blockIdx.y;
    const unsigned short* Kb = Kt + (size_t)b * 262144;
    const unsigned short* Vb = Vt + (size_t)b * 262144;
    const f32x4 z4 = {0.f, 0.f, 0.f, 0.f};
    f32x4 acc[4] = {z4, z4, z4, z4};
    const int m  = 16 * wave + (lane & 15);
    const int tq = (lane >> 4) * 8;
    #pragma unroll
    for (int it = 0; it < 4; it++) {
        int t0 = c * 128 + it * 32 + tq;
        bf16x8 a = *(const bf16x8*)&Kb[(size_t)m * 4096 + t0];
        #pragma unroll
        for (int nt = 0; nt < 4; nt++) {
            bf16x8 bb = *(const bf16x8*)&Vb[(size_t)(nt * 16 + (lane & 15)) * 4096 + t0];
            acc[nt] = MFMA16(a, bb, acc[nt]);
        }
    }
    float* P = Mf + (size_t)b * 4096;
    const int rowb = 16 * wave + (lane >> 4) * 4;
    #pragma unroll
    for (int nt = 0; nt < 4; nt++)
        #pragma unroll
        for (int reg = 0; reg < 4; reg++)
            atomicAdd(&P[(rowb + reg) * 64 + nt * 16 + (lane & 15)], acc[nt][reg]);
}

__global__ __launch_bounds__(256) void qm(
    const unsigned short* __restrict__ Q, const float* __restrict__ Mf,
    float* __restrict__ out) {
    __shared__ unsigned short Lm[64 * 72];
    const int lane = threadIdx.x & 63, wave = threadIdx.x >> 6;
    const int r0 = blockIdx.x * 64;
    const int b  = r0 >> 12;
    {
        const int tt = threadIdx.x;
        int h1 = tt >> 2, h2c = (tt & 3) * 16;
        const float* Mp = Mf + (size_t)b * 4096 + h1 * 64 + h2c;
        float vals[16];
        *(float4*)(vals + 0)  = *(const float4*)(Mp + 0);
        *(float4*)(vals + 4)  = *(const float4*)(Mp + 4);
        *(float4*)(vals + 8)  = *(const float4*)(Mp + 8);
        *(float4*)(vals + 12) = *(const float4*)(Mp + 12);
        #pragma unroll
        for (int u = 0; u < 16; u++) Lm[(h2c + u) * 72 + h1] = f2bf(vals[u]);
    }
    __syncthreads();
    const f32x4 z4 = {0.f, 0.f, 0.f, 0.f};
    f32x4 acc[4] = {z4, z4, z4, z4};
    const int rr = r0 + 16 * wave + (lane & 15);
    const int kq = (lane >> 4) * 8;
    #pragma unroll
    for (int ks = 0; ks < 2; ks++) {
        int k0 = ks * 32;
        bf16x8 a = *(const bf16x8*)&Q[(size_t)rr * 64 + k0 + kq];
        #pragma unroll
        for (int nt = 0; nt < 4; nt++) {
            bf16x8 bb = *(const bf16x8*)&Lm[(size_t)(nt * 16 + (lane & 15)) * 72 + k0 + kq];
            acc[nt] = MFMA16(a, bb, acc[nt]);
        }
    }
    const int rowb = r0 + 16 * wave + (lane >> 4) * 4;
    #pragma unroll
    for (int nt = 0; nt < 4; nt++)
        #pragma unroll
        for (int reg = 0; reg < 4; reg++)
            out[(size_t)(rowb + reg) * 64 + nt * 16 + (lane & 15)] = acc[nt][reg];
}

// ---------------------------------------------------------------------------
// Workspace layout:
//   mega:     WB [0,384K) · part [1M,9M) · Mt [9M,9M+32K)
//   fallback: WB [0,384K) · Mf [16M,16M+64K) · Q [17M) · Kt [19M) · Vt [21M)
extern "C" void kernel_launch(void* const* d_in, const int* in_sizes, int n_in,
                              void* d_out, int out_size, void* d_ws, size_t ws_size,
                              hipStream_t stream) {
    const float* idx = (const float*)d_in[0];
    const float* Wq  = (const float*)d_in[1];
    const float* bq  = (const float*)d_in[2];
    const float* Wk  = (const float*)d_in[3];
    const float* bk  = (const float*)d_in[4];
    const float* Wv  = (const float*)d_in[5];
    const float* bv  = (const float*)d_in[6];
    float* out = (float*)d_out;

    char* ws = (char*)d_ws;
    unsigned short* WB = (unsigned short*)(ws);
    float*          Pp = (float*)(ws + (1024u << 10));
    unsigned short* Mt = (unsigned short*)(ws + (9216u << 10));

    void* args[] = {(void*)&idx, (void*)&Wq, (void*)&bq, (void*)&Wk, (void*)&bk,
                    (void*)&Wv, (void*)&bv, (void*)&WB, (void*)&Pp, (void*)&Mt,
                    (void*)&out};
    hipError_t e = hipLaunchCooperativeKernel((const void*)mega, dim3(512), dim3(256),
                                              args, 0, stream);
    if (e != hipSuccess) {
        // Fallback: R8 4-kernel path.
        float*          Mf = (float*)(ws + (16384u << 10));
        unsigned short* Q  = (unsigned short*)(ws + (17408u << 10));
        unsigned short* Kt = (unsigned short*)(ws + (19456u << 10));
        unsigned short* Vt = (unsigned short*)(ws + (21504u << 10));
        hipLaunchKernelGGL(prep, dim3(96),    dim3(256), 0, stream, Wq, Wk, Wv, WB, Mf);
        hipLaunchKernelGGL(qkv,  dim3(512),   dim3(256), 0, stream,
                           idx, WB, bq, bk, bv, Q, Kt, Vt);
        hipLaunchKernelGGL(ktv,  dim3(32, 4), dim3(256), 0, stream, Kt, Vt, Mf);
        hipLaunchKernelGGL(qm,   dim3(256),   dim3(256), 0, stream, Q, Mf, out);
    }
}

// Round 3
// 123.451 us; speedup vs baseline: 2.4534x; 2.4534x over previous
//
#include <hip/hip_runtime.h>

// B=4, T=4096, E=1024, H=64.
// out = Q @ M_b,  M_b = (1/32) * K_b^T V_b,  Q/K/V = idx@W + b   (linear attention:
// reference applies no mask/softmax). Scale folded into Wk/bk.
//
// R10: 3 kernels. R9 lesson: cooperative grid.sync costs ~50-60us each on MI355X
// (8 XCDs, device-scope spin) -> kernel boundaries ARE the cheap global barrier.
// K2 fuses ktv: each block computes its 32-row K^T V contribution from its LDS
// tiles (Kt/Vt never touch global, -14MB traffic, -1 launch) and atomicAdds fp32
// into Mf (2M atomics / 16K addrs, L2-parallel). Mf zeroed in prep (ws poisoned).

typedef __attribute__((ext_vector_type(8))) short bf16x8;   // 8 bf16 = 4 VGPRs
typedef __attribute__((ext_vector_type(4))) float f32x4;    // MFMA C/D

#define MFMA16(a, b, c) __builtin_amdgcn_mfma_f32_16x16x32_bf16((a), (b), (c), 0, 0, 0)

__device__ __forceinline__ unsigned short f2bf(float f) {
    unsigned int u = __float_as_uint(f);
    u += 0x7fffu + ((u >> 16) & 1u);          // round-to-nearest-even
    return (unsigned short)(u >> 16);
}

// ---------------------------------------------------------------------------
// K0: weights -> MFMA-fragment order; zero the Mf accumulator (ws is poisoned).
// Chunk t = (kk*12 + nt)*64 + lane holds 8 bf16:
//   W^T[n][k], n = nt*16 + (lane&15), k = kk*32 + (lane>>4)*8 + j.
// n<64 -> Wq, n<128 -> Wk * 1/32, else Wv.   (W is [k][h] in memory)
__global__ void prep(const float* __restrict__ Wq, const float* __restrict__ Wk,
                     const float* __restrict__ Wv, unsigned short* __restrict__ WB,
                     float* __restrict__ Mf) {
    int t = blockIdx.x * 256 + threadIdx.x;   // 96 blocks -> 24576 chunks
    if (t < 16384) Mf[t] = 0.f;               // 4 * 64 * 64 fp32 accumulator
    int kki = t / 768;
    int rem = t - kki * 768;
    int nt = rem >> 6, lane = rem & 63;
    int n = nt * 16 + (lane & 15);
    int kb = kki * 32 + ((lane >> 4) * 8);
    int mm = n >> 6, h = n & 63;
    const float* W = (mm == 0) ? Wq : (mm == 1) ? Wk : Wv;
    float sc = (mm == 1) ? 0.03125f : 1.0f;
    bf16x8 v;
    #pragma unroll
    for (int j = 0; j < 8; j++) v[j] = (short)f2bf(W[(size_t)(kb + j) * 64 + h] * sc);
    *(bf16x8*)(WB + (size_t)t * 8) = v;
}

// ---------------------------------------------------------------------------
// K1: fused QKV projection + local K^T V contribution.
// Block = 32 rows, 4 waves; grid 512 (2 blocks/CU, 70.4KB LDS).
// Phase A: stage idx rows -> bf16 LDS. Phase B: 32-kk MFMA loop (B frags 2-deep
// register pipeline from L2-resident WB, A ds_read 1 ahead). Phase C: Q -> global
// (coalesced via LDS transpose); K,V -> LDS tiles Lk/Lv (reuse As). Phase D:
// M_part = Kt_loc @ Vt_loc^T (4 MFMAs/wave, K=32) -> atomicAdd into Mf[b].
__global__ __launch_bounds__(256, 2) void qkv_m(
    const float* __restrict__ idx, const unsigned short* __restrict__ WB,
    const float* __restrict__ bq, const float* __restrict__ bk, const float* __restrict__ bv,
    unsigned short* __restrict__ Q, float* __restrict__ Mf) {
    __shared__ unsigned short As[32 * 1032];   // 66048 B (stage; reused as Lk/Lv)
    __shared__ unsigned short Lq[32 * 68];     // 4352 B
    unsigned short* Lk = As;                   // [64][36] bf16, K local (h-major)
    unsigned short* Lv = As + 64 * 36;         // [64][36] bf16, V local

    const int tid = threadIdx.x, lane = tid & 63, w = tid >> 6;
    const int r0 = blockIdx.x * 32;

    // ---- phase A: stage 8 contiguous rows per wave ----
    {
        const float* src = idx + (size_t)(r0 + w * 8) * 1024;
        #pragma unroll
        for (int batch = 0; batch < 4; batch++) {
            float4 v[8];
            #pragma unroll
            for (int j = 0; j < 8; j++)
                v[j] = *(const float4*)(src + (size_t)(batch * 8 + j) * 256 + lane * 4);
            #pragma unroll
            for (int j = 0; j < 8; j++) {
                int i   = batch * 8 + j;
                int row = w * 8 + (i >> 2);
                int k   = (i & 3) * 256 + lane * 4;
                unsigned int lo = ((unsigned int)f2bf(v[j].y) << 16) | f2bf(v[j].x);
                unsigned int hi = ((unsigned int)f2bf(v[j].w) << 16) | f2bf(v[j].z);
                uint2 p; p.x = lo; p.y = hi;
                *(uint2*)(As + (size_t)row * 1032 + k) = p;
            }
        }
    }
    __syncthreads();

    // ---- phase B: projection MFMA loop ----
    const f32x4 z4 = {0.f, 0.f, 0.f, 0.f};
    f32x4 acc[2][3] = {{z4, z4, z4}, {z4, z4, z4}};
    {
        const unsigned short* a_base0 = As + (size_t)(lane & 15) * 1032 + ((lane >> 4) * 8);
        const unsigned short* a_base1 = a_base0 + 16 * 1032;
        bf16x8 a_c[2], b0[3], b1[3], b2[3];
        a_c[0] = *(const bf16x8*)a_base0;
        a_c[1] = *(const bf16x8*)a_base1;
        {
            const unsigned short* Bp0 = WB + (size_t)(lane * 8);
            const unsigned short* Bp1 = WB + (size_t)(12 * 64 + lane) * 8;
            #pragma unroll
            for (int j = 0; j < 3; j++) {
                b0[j] = *(const bf16x8*)(Bp0 + (w + j * 4) * 512);
                b1[j] = *(const bf16x8*)(Bp1 + (w + j * 4) * 512);
                b2[j] = b1[j];
            }
        }
        for (int kk = 0; kk < 32; kk++) {
            bf16x8 na0 = a_c[0], na1 = a_c[1];
            if (kk < 30) {
                const unsigned short* Bp = WB + (size_t)(((kk + 2) * 12) * 64 + lane) * 8;
                #pragma unroll
                for (int j = 0; j < 3; j++) b2[j] = *(const bf16x8*)(Bp + (w + j * 4) * 512);
            }
            if (kk < 31) {
                na0 = *(const bf16x8*)(a_base0 + (kk + 1) * 32);
                na1 = *(const bf16x8*)(a_base1 + (kk + 1) * 32);
            }
            #pragma unroll
            for (int j = 0; j < 3; j++) {
                acc[0][j] = MFMA16(a_c[0], b0[j], acc[0][j]);
                acc[1][j] = MFMA16(a_c[1], b0[j], acc[1][j]);
            }
            #pragma unroll
            for (int j = 0; j < 3; j++) { b0[j] = b1[j]; b1[j] = b2[j]; }
            a_c[0] = na0; a_c[1] = na1;
        }
    }

    // ---- phase C: bias + write Q/K/V into LDS (As A-reads done -> reuse) ----
    __syncthreads();
    {
        const int h     = w * 16 + (lane & 15);
        const int rbase = (lane >> 4) * 4;
        float bias0 = bq[h], bias1 = bk[h] * 0.03125f, bias2 = bv[h];
        #pragma unroll
        for (int rf = 0; rf < 2; rf++) {
            #pragma unroll
            for (int reg = 0; reg < 4; reg++) {
                int r = rf * 16 + rbase + reg;
                Lq[r * 68 + h] = f2bf(acc[rf][0][reg] + bias0);
                Lk[h * 36 + r] = f2bf(acc[rf][1][reg] + bias1);   // [h][t], pad 36
                Lv[h * 36 + r] = f2bf(acc[rf][2][reg] + bias2);
            }
        }
    }
    __syncthreads();

    // ---- Q to global, coalesced 16B/lane ----
    {
        int qr = tid >> 3, qh = (tid & 7) * 8;
        *(uint4*)(Q + (size_t)(r0 + qr) * 64 + qh) = *(const uint4*)(Lq + qr * 68 + qh);
    }

    // ---- phase D: M contribution (K=t=32) + atomicAdd ----
    {
        const int tq = (lane >> 4) * 8;
        bf16x8 a = *(const bf16x8*)&Lk[(16 * w + (lane & 15)) * 36 + tq];
        f32x4 accM[4];
        #pragma unroll
        for (int nt = 0; nt < 4; nt++) {
            bf16x8 bb = *(const bf16x8*)&Lv[(nt * 16 + (lane & 15)) * 36 + tq];
            accM[nt] = MFMA16(a, bb, z4);
        }
        float* P = Mf + (size_t)(r0 >> 12) * 4096;
        const int rowb = 16 * w + (lane >> 4) * 4;
        #pragma unroll
        for (int nt = 0; nt < 4; nt++)
            #pragma unroll
            for (int reg = 0; reg < 4; reg++)
                atomicAdd(&P[(rowb + reg) * 64 + nt * 16 + (lane & 15)], accM[nt][reg]);
    }
}

// ---------------------------------------------------------------------------
// K2: out[r][h2] = Q[r][:] @ M_b[:, h2], fp32 out. M converted fp32->bf16
// fragments in LDS per block (transposed [h2][h1], stride 72: 2-way banks, free).
__global__ __launch_bounds__(256) void qm(
    const unsigned short* __restrict__ Q, const float* __restrict__ Mf,
    float* __restrict__ out) {
    __shared__ unsigned short Lm[64 * 72];
    const int lane = threadIdx.x & 63, wave = threadIdx.x >> 6;
    const int r0 = blockIdx.x * 64;
    const int b  = r0 >> 12;
    {
        const int tt = threadIdx.x;
        int h1 = tt >> 2, h2c = (tt & 3) * 16;
        const float* Mp = Mf + (size_t)b * 4096 + h1 * 64 + h2c;
        float vals[16];
        *(float4*)(vals + 0)  = *(const float4*)(Mp + 0);
        *(float4*)(vals + 4)  = *(const float4*)(Mp + 4);
        *(float4*)(vals + 8)  = *(const float4*)(Mp + 8);
        *(float4*)(vals + 12) = *(const float4*)(Mp + 12);
        #pragma unroll
        for (int u = 0; u < 16; u++) Lm[(h2c + u) * 72 + h1] = f2bf(vals[u]);
    }
    __syncthreads();
    const f32x4 z4 = {0.f, 0.f, 0.f, 0.f};
    f32x4 acc[4] = {z4, z4, z4, z4};
    const int rr = r0 + 16 * wave + (lane & 15);
    const int kq = (lane >> 4) * 8;
    #pragma unroll
    for (int ks = 0; ks < 2; ks++) {
        int k0 = ks * 32;
        bf16x8 a = *(const bf16x8*)&Q[(size_t)rr * 64 + k0 + kq];
        #pragma unroll
        for (int nt = 0; nt < 4; nt++) {
            bf16x8 bb = *(const bf16x8*)&Lm[(size_t)(nt * 16 + (lane & 15)) * 72 + k0 + kq];
            acc[nt] = MFMA16(a, bb, acc[nt]);
        }
    }
    const int rowb = r0 + 16 * wave + (lane >> 4) * 4;
    #pragma unroll
    for (int nt = 0; nt < 4; nt++)
        #pragma unroll
        for (int reg = 0; reg < 4; reg++)
            out[(size_t)(rowb + reg) * 64 + nt * 16 + (lane & 15)] = acc[nt][reg];
}

// ---------------------------------------------------------------------------
// Workspace layout:
//   [0, 384K)        WB
//   [1M, 1M+64K)     Mf (fp32 M accumulator, zeroed by prep)
//   [2M, 4M)         Q
extern "C" void kernel_launch(void* const* d_in, const int* in_sizes, int n_in,
                              void* d_out, int out_size, void* d_ws, size_t ws_size,
                              hipStream_t stream) {
    const float* idx = (const float*)d_in[0];
    const float* Wq  = (const float*)d_in[1];
    const float* bq  = (const float*)d_in[2];
    const float* Wk  = (const float*)d_in[3];
    const float* bk  = (const float*)d_in[4];
    const float* Wv  = (const float*)d_in[5];
    const float* bv  = (const float*)d_in[6];
    float* out = (float*)d_out;

    char* ws = (char*)d_ws;
    unsigned short* WB = (unsigned short*)(ws);
    float*          Mf = (float*)(ws + (1024u << 10));
    unsigned short* Q  = (unsigned short*)(ws + (2048u << 10));

    hipLaunchKernelGGL(prep,  dim3(96),  dim3(256), 0, stream, Wq, Wk, Wv, WB, Mf);
    hipLaunchKernelGGL(qkv_m, dim3(512), dim3(256), 0, stream,
                       idx, WB, bq, bk, bv, Q, Mf);
    hipLaunchKernelGGL(qm,    dim3(256), dim3(256), 0, stream, Q, Mf, out);
}